// Round 1
// baseline (1971.037 us; speedup 1.0000x reference)
//
#include <hip/hip_runtime.h>
#include <math.h>

// Problem constants
#define B_   8
#define C_   128
#define C2_  256
#define H_   128
#define W_   128
#define HW_  16384
#define CR_  32
#define EPS_ 1e-5f
#define NS_  32     // n-splits for sim partial sums

// ---------------------------------------------------------------------------
// Kernel 1: global average pool over concat(x1,x2) -> avg[B][2C]
// ---------------------------------------------------------------------------
__global__ __launch_bounds__(256) void avgpool_kernel(
    const float* __restrict__ x1, const float* __restrict__ x2,
    float* __restrict__ avg)
{
    int bc = blockIdx.x;              // b*C2 + c
    int b = bc / C2_, c = bc % C2_;
    const float* src = (c < C_) ? (x1 + ((size_t)b * C_ + c) * HW_)
                                : (x2 + ((size_t)b * C_ + (c - C_)) * HW_);
    float s = 0.f;
    for (int i = threadIdx.x; i < HW_; i += 256) s += src[i];
    #pragma unroll
    for (int off = 32; off > 0; off >>= 1) s += __shfl_xor(s, off, 64);
    __shared__ float ls[4];
    int lane = threadIdx.x & 63, wid = threadIdx.x >> 6;
    if (lane == 0) ls[wid] = s;
    __syncthreads();
    if (threadIdx.x == 0) {
        avg[bc] = (ls[0] + ls[1] + ls[2] + ls[3]) * (1.f / (float)HW_);
    }
}

// ---------------------------------------------------------------------------
// Kernel 2: SE MLP  h=relu(avg@w1^T)  se=sigmoid(h@w2^T)   (tiny, 1 block)
// w1: [CR][C2], w2: [C2][CR]
// ---------------------------------------------------------------------------
__global__ __launch_bounds__(256) void se_mlp_kernel(
    const float* __restrict__ avg, const float* __restrict__ w1,
    const float* __restrict__ w2, float* __restrict__ se)
{
    __shared__ float s_avg[B_ * C2_];   // 2048
    __shared__ float s_h[B_ * CR_];     // 256
    for (int i = threadIdx.x; i < B_ * C2_; i += 256) s_avg[i] = avg[i];
    __syncthreads();
    {
        int i = threadIdx.x;            // exactly B*CR = 256
        int b = i / CR_, j = i % CR_;
        float s = 0.f;
        for (int k = 0; k < C2_; ++k) s += s_avg[b * C2_ + k] * w1[j * C2_ + k];
        s_h[i] = fmaxf(s, 0.f);
    }
    __syncthreads();
    for (int i = threadIdx.x; i < B_ * C2_; i += 256) {
        int b = i / C2_, c = i % C2_;
        float s = 0.f;
        #pragma unroll
        for (int j = 0; j < CR_; ++j) s += s_h[b * CR_ + j] * w2[c * CR_ + j];
        se[i] = 1.f / (1.f + expf(-s));
    }
}

// ---------------------------------------------------------------------------
// Kernel 3: 3x3 conv (SAME) over SE-scaled concat input + BN + ReLU -> y
// Block: 32x32 spatial tile x 16 output channels. ci staged in chunks of 8.
// SE scale fused into the staging load (concat never materialized).
// ---------------------------------------------------------------------------
#define TILE  32
#define CO_T  16
#define CI_T  8

__global__ __launch_bounds__(256) void conv_kernel(
    const float* __restrict__ x1, const float* __restrict__ x2,
    const float* __restrict__ se, const float* __restrict__ conv_w,
    const float* __restrict__ bn_gamma, const float* __restrict__ bn_beta,
    const float* __restrict__ bn_mean, const float* __restrict__ bn_var,
    float* __restrict__ y)
{
    __shared__ float in_s[CI_T * 34 * 34];                 // 9248 floats
    __shared__ __align__(16) float w_s[CI_T * 9 * CO_T];   // [ci][k][co], 1152
    __shared__ float se_s[C2_];

    int tid = threadIdx.x;
    int tile = blockIdx.x;            // 0..15
    int cog  = blockIdx.y;            // 0..7
    int b    = blockIdx.z;            // 0..7
    int h0 = (tile >> 2) * TILE;
    int w0 = (tile & 3) * TILE;
    int co0 = cog * CO_T;

    for (int i = tid; i < C2_; i += 256) se_s[i] = se[b * C2_ + i];

    float acc[CO_T * 4];
    #pragma unroll
    for (int i = 0; i < CO_T * 4; ++i) acc[i] = 0.f;

    int tw = tid & 31;   // output col within tile
    int th = tid >> 5;   // 0..7; rows th, th+8, th+16, th+24

    for (int chunk = 0; chunk < C2_ / CI_T; ++chunk) {
        int cbase = chunk * CI_T;
        __syncthreads();
        // stage input (with zero pad + SE scale)
        for (int idx = tid; idx < CI_T * 34 * 34; idx += 256) {
            int ci  = idx / (34 * 34);
            int rem = idx - ci * 34 * 34;
            int yy  = rem / 34;
            int xx  = rem - yy * 34;
            int gh = h0 + yy - 1;
            int gw = w0 + xx - 1;
            int cg = cbase + ci;
            float v = 0.f;
            if ((unsigned)gh < (unsigned)H_ && (unsigned)gw < (unsigned)W_) {
                const float* src = (cg < C_) ? x1 : x2;
                int cc = (cg < C_) ? cg : cg - C_;
                v = src[(((size_t)b * C_ + cc) * H_ + gh) * W_ + gw] * se_s[cg];
            }
            in_s[idx] = v;
        }
        // stage weights: global ((co*C2+ci)*9+k) -> LDS [ci][k][co]
        for (int idx = tid; idx < CO_T * CI_T * 9; idx += 256) {
            int co  = idx / (CI_T * 9);
            int rem = idx - co * CI_T * 9;
            int ci  = rem / 9;
            int k   = rem - ci * 9;
            w_s[(ci * 9 + k) * CO_T + co] =
                conv_w[((size_t)(co0 + co) * C2_ + (cbase + ci)) * 9 + k];
        }
        __syncthreads();
        // compute
        for (int ci = 0; ci < CI_T; ++ci) {
            #pragma unroll
            for (int k = 0; k < 9; ++k) {
                int kh = k / 3, kw = k - kh * 3;
                const float4* wp = (const float4*)&w_s[(ci * 9 + k) * CO_T];
                float4 wa = wp[0], wb = wp[1], wc = wp[2], wd = wp[3];
                float wreg[16] = {wa.x, wa.y, wa.z, wa.w, wb.x, wb.y, wb.z, wb.w,
                                  wc.x, wc.y, wc.z, wc.w, wd.x, wd.y, wd.z, wd.w};
                float a0 = in_s[(ci * 34 + (th + 0  + kh)) * 34 + tw + kw];
                float a1 = in_s[(ci * 34 + (th + 8  + kh)) * 34 + tw + kw];
                float a2 = in_s[(ci * 34 + (th + 16 + kh)) * 34 + tw + kw];
                float a3 = in_s[(ci * 34 + (th + 24 + kh)) * 34 + tw + kw];
                #pragma unroll
                for (int co = 0; co < CO_T; ++co) {
                    acc[co * 4 + 0] = fmaf(wreg[co], a0, acc[co * 4 + 0]);
                    acc[co * 4 + 1] = fmaf(wreg[co], a1, acc[co * 4 + 1]);
                    acc[co * 4 + 2] = fmaf(wreg[co], a2, acc[co * 4 + 2]);
                    acc[co * 4 + 3] = fmaf(wreg[co], a3, acc[co * 4 + 3]);
                }
            }
        }
    }
    // epilogue: BN + ReLU, write y
    #pragma unroll
    for (int co = 0; co < CO_T; ++co) {
        int c = co0 + co;
        float inv = bn_gamma[c] * rsqrtf(bn_var[c] + EPS_);
        float add = bn_beta[c] - bn_mean[c] * inv;
        #pragma unroll
        for (int r = 0; r < 4; ++r) {
            int oh = h0 + th + r * 8;
            int ow = w0 + tw;
            float v = fmaxf(acc[co * 4 + r] * inv + add, 0.f);
            y[(((size_t)b * C_ + c) * H_ + oh) * W_ + ow] = v;
        }
    }
}

// ---------------------------------------------------------------------------
// Kernel 4: sim partials.  simp[ns][b][c][d] = sum_{n in slice} y[b,c,n]*y[b,d,n]
// Block = one (ns,b); 256 threads as 16x16, each owns an 8x8 sub-tile.
// ---------------------------------------------------------------------------
__global__ __launch_bounds__(256) void sim_kernel(
    const float* __restrict__ y, float* __restrict__ simp)
{
    __shared__ __align__(16) float qs[32 * 132];   // [nn][c], padded to 132
    int ns = blockIdx.x, b = blockIdx.y;
    int n0 = ns * (HW_ / NS_);                     // 512-wide slice
    const float* q = y + (size_t)b * C_ * HW_;
    int tid = threadIdx.x;
    int td = tid & 15;
    int tc = tid >> 4;
    int c0 = tc * 8, d0 = td * 8;

    float acc[64];
    #pragma unroll
    for (int i = 0; i < 64; ++i) acc[i] = 0.f;

    for (int nb = 0; nb < (HW_ / NS_) / 32; ++nb) {   // 16 iterations
        __syncthreads();
        for (int idx = tid; idx < C_ * 32; idx += 256) {
            int c = idx >> 5;
            int nn = idx & 31;
            qs[nn * 132 + c] = q[(size_t)c * HW_ + n0 + nb * 32 + nn];
        }
        __syncthreads();
        for (int nn = 0; nn < 32; ++nn) {
            const float4* ap = (const float4*)&qs[nn * 132 + c0];
            const float4* bp = (const float4*)&qs[nn * 132 + d0];
            float4 a01 = ap[0], a23 = ap[1];
            float4 b01 = bp[0], b23 = bp[1];
            float av[8] = {a01.x, a01.y, a01.z, a01.w, a23.x, a23.y, a23.z, a23.w};
            float bv[8] = {b01.x, b01.y, b01.z, b01.w, b23.x, b23.y, b23.z, b23.w};
            #pragma unroll
            for (int i = 0; i < 8; ++i)
                #pragma unroll
                for (int j = 0; j < 8; ++j)
                    acc[i * 8 + j] = fmaf(av[i], bv[j], acc[i * 8 + j]);
        }
    }
    float* dst = simp + (size_t)(ns * B_ + b) * C_ * C_;
    #pragma unroll
    for (int i = 0; i < 8; ++i)
        #pragma unroll
        for (int j = 0; j < 8; ++j)
            dst[(c0 + i) * C_ + (d0 + j)] = acc[i * 8 + j];
}

// ---------------------------------------------------------------------------
// Kernel 5: reduce partials + softmax(-sim) -> P[b][c][d]
// (softmax(rowmax - sim) == softmax(-sim): shift invariance)
// ---------------------------------------------------------------------------
__global__ __launch_bounds__(128) void softmax_kernel(
    const float* __restrict__ simp, float* __restrict__ P)
{
    int bc = blockIdx.x;          // b*C + c
    int b = bc / C_, c = bc % C_;
    int d = threadIdx.x;          // 0..127
    float s = 0.f;
    for (int ns = 0; ns < NS_; ++ns)
        s += simp[((size_t)(ns * B_ + b) * C_ + c) * C_ + d];
    float v = -s;
    float m = v;
    #pragma unroll
    for (int off = 32; off > 0; off >>= 1) m = fmaxf(m, __shfl_xor(m, off, 64));
    __shared__ float sm[2], ss[2];
    int wid = threadIdx.x >> 6;
    if ((threadIdx.x & 63) == 0) sm[wid] = m;
    __syncthreads();
    m = fmaxf(sm[0], sm[1]);
    float p = expf(v - m);
    float sum = p;
    #pragma unroll
    for (int off = 32; off > 0; off >>= 1) sum += __shfl_xor(sum, off, 64);
    if ((threadIdx.x & 63) == 0) ss[wid] = sum;
    __syncthreads();
    sum = ss[0] + ss[1];
    P[(size_t)bc * C_ + d] = p / sum;
}

// ---------------------------------------------------------------------------
// Kernel 6: feat = P @ y; out = gamma*feat + y
// Block: 256 n-columns x 32 c-rows. P tile staged [d][i] for b128 broadcasts.
// ---------------------------------------------------------------------------
__global__ __launch_bounds__(256) void feat_kernel(
    const float* __restrict__ y, const float* __restrict__ P,
    const float* __restrict__ gamma, float* __restrict__ out)
{
    __shared__ __align__(16) float Ps[C_ * 32];   // Ps[d*32+i] = P[b][c0+i][d]
    int nc = blockIdx.x;   // 0..63
    int cg = blockIdx.y;   // 0..3
    int b  = blockIdx.z;
    int c0 = cg * 32;
    int tid = threadIdx.x;
    int n = nc * 256 + tid;

    for (int idx = tid; idx < C_ * 32; idx += 256) {
        int d = idx >> 5;
        int i = idx & 31;
        Ps[idx] = P[((size_t)b * C_ + c0 + i) * C_ + d];
    }
    __syncthreads();

    float acc[32];
    #pragma unroll
    for (int i = 0; i < 32; ++i) acc[i] = 0.f;
    const float* yb = y + (size_t)b * C_ * HW_;
    #pragma unroll 4
    for (int d = 0; d < C_; ++d) {
        float v = yb[(size_t)d * HW_ + n];
        const float4* pp = (const float4*)&Ps[d * 32];
        #pragma unroll
        for (int q4 = 0; q4 < 8; ++q4) {
            float4 w4 = pp[q4];
            acc[q4 * 4 + 0] = fmaf(w4.x, v, acc[q4 * 4 + 0]);
            acc[q4 * 4 + 1] = fmaf(w4.y, v, acc[q4 * 4 + 1]);
            acc[q4 * 4 + 2] = fmaf(w4.z, v, acc[q4 * 4 + 2]);
            acc[q4 * 4 + 3] = fmaf(w4.w, v, acc[q4 * 4 + 3]);
        }
    }
    float g = gamma[0];
    #pragma unroll
    for (int i = 0; i < 32; ++i) {
        size_t o = ((size_t)b * C_ + c0 + i) * HW_ + n;
        out[o] = g * acc[i] + y[o];
    }
}

// ---------------------------------------------------------------------------
extern "C" void kernel_launch(void* const* d_in, const int* in_sizes, int n_in,
                              void* d_out, int out_size, void* d_ws, size_t ws_size,
                              hipStream_t stream)
{
    const float* x1       = (const float*)d_in[0];
    const float* x2       = (const float*)d_in[1];
    const float* se_w1    = (const float*)d_in[2];
    const float* se_w2    = (const float*)d_in[3];
    const float* conv_w   = (const float*)d_in[4];
    const float* bn_gamma = (const float*)d_in[5];
    const float* bn_beta  = (const float*)d_in[6];
    const float* bn_mean  = (const float*)d_in[7];
    const float* bn_var   = (const float*)d_in[8];
    const float* gamma    = (const float*)d_in[9];
    float* out = (float*)d_out;

    char* ws = (char*)d_ws;
    float* avg  = (float*)(ws);                            // 2048 f
    float* se   = (float*)(ws + 8192);                     // 2048 f
    float* P    = (float*)(ws + 16384);                    // 131072 f (512 KB)
    float* simp = (float*)(ws + 540672);                   // NS*131072 f (16 MB)
    float* y    = (float*)(ws + 540672 + 16777216);        // 16777216 f (64 MB)

    avgpool_kernel<<<dim3(B_ * C2_), 256, 0, stream>>>(x1, x2, avg);
    se_mlp_kernel<<<dim3(1), 256, 0, stream>>>(avg, se_w1, se_w2, se);
    conv_kernel<<<dim3(16, 8, B_), 256, 0, stream>>>(x1, x2, se, conv_w,
                                                     bn_gamma, bn_beta, bn_mean,
                                                     bn_var, y);
    sim_kernel<<<dim3(NS_, B_), 256, 0, stream>>>(y, simp);
    softmax_kernel<<<dim3(B_ * C_), 128, 0, stream>>>(simp, P);
    feat_kernel<<<dim3(64, 4, B_), 256, 0, stream>>>(y, P, gamma, out);
}

// Round 2
// 546.558 us; speedup vs baseline: 3.6063x; 3.6063x over previous
//
#include <hip/hip_runtime.h>
#include <math.h>

// Problem constants
#define B_   8
#define C_   128
#define C2_  256
#define H_   128
#define W_   128
#define HW_  16384
#define CR_  32
#define EPS_ 1e-5f
#define NS_  32     // n-splits for sim partial sums

typedef _Float16 f16;
typedef f16 f16x8 __attribute__((ext_vector_type(8)));
typedef float f32x4 __attribute__((ext_vector_type(4)));

// ---------------------------------------------------------------------------
// Kernel 1: global average pool over concat(x1,x2) -> avg[B][2C]
// ---------------------------------------------------------------------------
__global__ __launch_bounds__(256) void avgpool_kernel(
    const float* __restrict__ x1, const float* __restrict__ x2,
    float* __restrict__ avg)
{
    int bc = blockIdx.x;              // b*C2 + c
    int b = bc / C2_, c = bc % C2_;
    const float* src = (c < C_) ? (x1 + ((size_t)b * C_ + c) * HW_)
                                : (x2 + ((size_t)b * C_ + (c - C_)) * HW_);
    float s = 0.f;
    for (int i = threadIdx.x; i < HW_; i += 256) s += src[i];
    #pragma unroll
    for (int off = 32; off > 0; off >>= 1) s += __shfl_xor(s, off, 64);
    __shared__ float ls[4];
    int lane = threadIdx.x & 63, wid = threadIdx.x >> 6;
    if (lane == 0) ls[wid] = s;
    __syncthreads();
    if (threadIdx.x == 0) {
        avg[bc] = (ls[0] + ls[1] + ls[2] + ls[3]) * (1.f / (float)HW_);
    }
}

// ---------------------------------------------------------------------------
// Kernel 2: SE MLP  h=relu(avg@w1^T)  se=sigmoid(h@w2^T)   (tiny, 1 block)
// ---------------------------------------------------------------------------
__global__ __launch_bounds__(256) void se_mlp_kernel(
    const float* __restrict__ avg, const float* __restrict__ w1,
    const float* __restrict__ w2, float* __restrict__ se)
{
    __shared__ float s_avg[B_ * C2_];
    __shared__ float s_h[B_ * CR_];
    for (int i = threadIdx.x; i < B_ * C2_; i += 256) s_avg[i] = avg[i];
    __syncthreads();
    {
        int i = threadIdx.x;            // exactly B*CR = 256
        int b = i / CR_, j = i % CR_;
        float s = 0.f;
        for (int k = 0; k < C2_; ++k) s += s_avg[b * C2_ + k] * w1[j * C2_ + k];
        s_h[i] = fmaxf(s, 0.f);
    }
    __syncthreads();
    for (int i = threadIdx.x; i < B_ * C2_; i += 256) {
        int b = i / C2_, c = i % C2_;
        float s = 0.f;
        #pragma unroll
        for (int j = 0; j < CR_; ++j) s += s_h[b * CR_ + j] * w2[c * CR_ + j];
        se[i] = 1.f / (1.f + expf(-s));
    }
}

// ---------------------------------------------------------------------------
// Kernel 3a: weight repack  conv_w[co][2C][3][3] fp32 -> wt[9][8][128][32] fp16
// (tap-major, ci-chunk, co, ci-in-chunk: A-fragment reads become 16B contiguous)
// ---------------------------------------------------------------------------
__global__ __launch_bounds__(256) void wt_build_kernel(
    const float* __restrict__ conv_w, f16* __restrict__ wt)
{
    int idx = blockIdx.x * 256 + threadIdx.x;   // < 9*8*128*32 = 294912 exact
    int ci = idx & 31;
    int co = (idx >> 5) & 127;
    int cc = (idx >> 12) & 7;
    int t  = idx >> 15;
    wt[idx] = (f16)conv_w[((size_t)co * C2_ + cc * 32 + ci) * 9 + t];
}

// ---------------------------------------------------------------------------
// Kernel 3b: xs build — NHWC fp16 of concat(x1,x2)*se, LDS-transposed.
// Block = (h, bb). XOR-swizzled LDS tile [128 w][136 c] breaks bank conflicts.
// ---------------------------------------------------------------------------
__global__ __launch_bounds__(256) void xs_build_kernel(
    const float* __restrict__ x1, const float* __restrict__ x2,
    const float* __restrict__ se, f16* __restrict__ xs, int b0)
{
    __shared__ f16 T[W_ * 136];
    int h = blockIdx.x, bb = blockIdx.y, b = b0 + bb;
    int tid = threadIdx.x;
    f16* out = xs + ((size_t)bb * H_ + h) * W_ * C2_;
    for (int p = 0; p < 2; ++p) {
        const float* src = p ? x2 : x1;
        __syncthreads();
        // load coalesced (w-inner), scale, cvt, transposed+swizzled LDS write
        for (int idx = tid; idx < C_ * 32; idx += 256) {
            int c = idx >> 5, w4 = (idx & 31) << 2;
            const float4 v = *(const float4*)&src[(((size_t)b * C_ + c) * H_ + h) * W_ + w4];
            float s = se[b * C2_ + p * C_ + c];
            int cs = c ^ (8 * ((w4 >> 2) & 15));   // swizzle const across the 4 w's
            T[(w4 + 0) * 136 + cs] = (f16)(v.x * s);
            T[(w4 + 1) * 136 + cs] = (f16)(v.y * s);
            T[(w4 + 2) * 136 + cs] = (f16)(v.z * s);
            T[(w4 + 3) * 136 + cs] = (f16)(v.w * s);
        }
        __syncthreads();
        // write out c-inner (b128 LDS reads, 16B global stores)
        for (int u = tid; u < W_ * 16; u += 256) {
            int w = u >> 4, o = u & 15;
            f16x8 v = *(const f16x8*)&T[w * 136 + ((o * 8) ^ (8 * ((w >> 2) & 15)))];
            *(f16x8*)&out[w * C2_ + p * C_ + o * 8] = v;
        }
    }
}

// ---------------------------------------------------------------------------
// Kernel 3c: conv as implicit GEMM with fp16 MFMA.
// Block = (h, bb): M=128 co x N=128 w, K = 8 ci-chunks x 9 taps x 32.
// 4 waves in 2x2; each wave 4x4 tiles of 16x16x32 MFMA.
// A (weights) direct from L1/L2 (16B/lane); B (x) from LDS (pad-40 -> conflict-free).
// ---------------------------------------------------------------------------
#define XROW 130
#define XPAD 40

__global__ __launch_bounds__(256, 3) void conv_mfma_kernel(
    const f16* __restrict__ xs, const f16* __restrict__ wt,
    const float* __restrict__ bn_gamma, const float* __restrict__ bn_beta,
    const float* __restrict__ bn_mean, const float* __restrict__ bn_var,
    float* __restrict__ y, int b0)
{
    __shared__ f16 Xs[3 * XROW * XPAD];   // 31200 B
    int h = blockIdx.x, bb = blockIdx.y, b = b0 + bb;
    int tid = threadIdx.x;
    int wave = tid >> 6, lane = tid & 63;
    int wm = wave >> 1, wn = wave & 1;
    int lr = lane & 15, kg = lane >> 4;
    const f16* xsb = xs + (size_t)bb * ((size_t)H_ * W_ * C2_);

    f32x4 acc[4][4];
    #pragma unroll
    for (int i = 0; i < 4; ++i)
        #pragma unroll
        for (int j = 0; j < 4; ++j)
            #pragma unroll
            for (int r = 0; r < 4; ++r) acc[i][j][r] = 0.f;

    for (int cc = 0; cc < 8; ++cc) {
        __syncthreads();
        // stage 32ci x 3rows x 130cols (zero-pad borders), ci-inner
        for (int u = tid; u < 3 * XROW * 4; u += 256) {
            int r = u / (XROW * 4);
            int rem = u - r * (XROW * 4);
            int col = rem >> 2, q = rem & 3;
            int gh = h + r - 1, gw = col - 1;
            f16x8 v;
            #pragma unroll
            for (int z = 0; z < 8; ++z) v[z] = (f16)0.f;
            if ((unsigned)gh < (unsigned)H_ && (unsigned)gw < (unsigned)W_)
                v = *(const f16x8*)&xsb[((size_t)(gh * W_ + gw)) * C2_ + cc * 32 + q * 8];
            *(f16x8*)&Xs[(r * XROW + col) * XPAD + q * 8] = v;
        }
        __syncthreads();
        #pragma unroll
        for (int t = 0; t < 9; ++t) {
            const int dh = t / 3, dw = t % 3;
            f16x8 af[4], bf[4];
            const f16* wbase = wt + ((size_t)(t * 8 + cc) * C_) * 32;
            #pragma unroll
            for (int i = 0; i < 4; ++i)
                af[i] = *(const f16x8*)&wbase[(wm * 64 + i * 16 + lr) * 32 + kg * 8];
            #pragma unroll
            for (int j = 0; j < 4; ++j)
                bf[j] = *(const f16x8*)&Xs[(dh * XROW + (wn * 64 + j * 16 + lr + dw)) * XPAD + kg * 8];
            #pragma unroll
            for (int i = 0; i < 4; ++i)
                #pragma unroll
                for (int j = 0; j < 4; ++j)
                    acc[i][j] = __builtin_amdgcn_mfma_f32_16x16x32_f16(af[i], bf[j], acc[i][j], 0, 0, 0);
        }
    }
    // epilogue: BN + ReLU.  D layout: col=lane&15, row=(lane>>4)*4+reg
    #pragma unroll
    for (int i = 0; i < 4; ++i) {
        #pragma unroll
        for (int r = 0; r < 4; ++r) {
            int c = wm * 64 + i * 16 + kg * 4 + r;
            float inv = bn_gamma[c] * rsqrtf(bn_var[c] + EPS_);
            float add = bn_beta[c] - bn_mean[c] * inv;
            float* yrow = y + (((size_t)b * C_ + c) * H_ + h) * W_;
            #pragma unroll
            for (int j = 0; j < 4; ++j) {
                int n = wn * 64 + j * 16 + lr;
                yrow[n] = fmaxf(acc[i][j][r] * inv + add, 0.f);
            }
        }
    }
}

// ---------------------------------------------------------------------------
// FALLBACK conv (round-1 fp32 version) — used only if ws_size is too small
// ---------------------------------------------------------------------------
#define TILE  32
#define CO_T  16
#define CI_T  8

__global__ __launch_bounds__(256) void conv_kernel(
    const float* __restrict__ x1, const float* __restrict__ x2,
    const float* __restrict__ se, const float* __restrict__ conv_w,
    const float* __restrict__ bn_gamma, const float* __restrict__ bn_beta,
    const float* __restrict__ bn_mean, const float* __restrict__ bn_var,
    float* __restrict__ y)
{
    __shared__ float in_s[CI_T * 34 * 34];
    __shared__ __align__(16) float w_s[CI_T * 9 * CO_T];
    __shared__ float se_s[C2_];

    int tid = threadIdx.x;
    int tile = blockIdx.x;
    int cog  = blockIdx.y;
    int b    = blockIdx.z;
    int h0 = (tile >> 2) * TILE;
    int w0 = (tile & 3) * TILE;
    int co0 = cog * CO_T;

    for (int i = tid; i < C2_; i += 256) se_s[i] = se[b * C2_ + i];

    float acc[CO_T * 4];
    #pragma unroll
    for (int i = 0; i < CO_T * 4; ++i) acc[i] = 0.f;

    int tw = tid & 31;
    int th = tid >> 5;

    for (int chunk = 0; chunk < C2_ / CI_T; ++chunk) {
        int cbase = chunk * CI_T;
        __syncthreads();
        for (int idx = tid; idx < CI_T * 34 * 34; idx += 256) {
            int ci  = idx / (34 * 34);
            int rem = idx - ci * 34 * 34;
            int yy  = rem / 34;
            int xx  = rem - yy * 34;
            int gh = h0 + yy - 1;
            int gw = w0 + xx - 1;
            int cg = cbase + ci;
            float v = 0.f;
            if ((unsigned)gh < (unsigned)H_ && (unsigned)gw < (unsigned)W_) {
                const float* src = (cg < C_) ? x1 : x2;
                int cc2 = (cg < C_) ? cg : cg - C_;
                v = src[(((size_t)b * C_ + cc2) * H_ + gh) * W_ + gw] * se_s[cg];
            }
            in_s[idx] = v;
        }
        for (int idx = tid; idx < CO_T * CI_T * 9; idx += 256) {
            int co  = idx / (CI_T * 9);
            int rem = idx - co * CI_T * 9;
            int ci  = rem / 9;
            int k   = rem - ci * 9;
            w_s[(ci * 9 + k) * CO_T + co] =
                conv_w[((size_t)(co0 + co) * C2_ + (cbase + ci)) * 9 + k];
        }
        __syncthreads();
        for (int ci = 0; ci < CI_T; ++ci) {
            #pragma unroll
            for (int k = 0; k < 9; ++k) {
                int kh = k / 3, kw = k - kh * 3;
                const float4* wp = (const float4*)&w_s[(ci * 9 + k) * CO_T];
                float4 wa = wp[0], wb = wp[1], wc = wp[2], wd = wp[3];
                float wreg[16] = {wa.x, wa.y, wa.z, wa.w, wb.x, wb.y, wb.z, wb.w,
                                  wc.x, wc.y, wc.z, wc.w, wd.x, wd.y, wd.z, wd.w};
                float a0 = in_s[(ci * 34 + (th + 0  + kh)) * 34 + tw + kw];
                float a1 = in_s[(ci * 34 + (th + 8  + kh)) * 34 + tw + kw];
                float a2 = in_s[(ci * 34 + (th + 16 + kh)) * 34 + tw + kw];
                float a3 = in_s[(ci * 34 + (th + 24 + kh)) * 34 + tw + kw];
                #pragma unroll
                for (int co = 0; co < CO_T; ++co) {
                    acc[co * 4 + 0] = fmaf(wreg[co], a0, acc[co * 4 + 0]);
                    acc[co * 4 + 1] = fmaf(wreg[co], a1, acc[co * 4 + 1]);
                    acc[co * 4 + 2] = fmaf(wreg[co], a2, acc[co * 4 + 2]);
                    acc[co * 4 + 3] = fmaf(wreg[co], a3, acc[co * 4 + 3]);
                }
            }
        }
    }
    #pragma unroll
    for (int co = 0; co < CO_T; ++co) {
        int c = co0 + co;
        float inv = bn_gamma[c] * rsqrtf(bn_var[c] + EPS_);
        float add = bn_beta[c] - bn_mean[c] * inv;
        #pragma unroll
        for (int r = 0; r < 4; ++r) {
            int oh = h0 + th + r * 8;
            int ow = w0 + tw;
            float v = fmaxf(acc[co * 4 + r] * inv + add, 0.f);
            y[(((size_t)b * C_ + c) * H_ + oh) * W_ + ow] = v;
        }
    }
}

// ---------------------------------------------------------------------------
// Kernel 4: sim partials (unchanged)
// ---------------------------------------------------------------------------
__global__ __launch_bounds__(256) void sim_kernel(
    const float* __restrict__ y, float* __restrict__ simp)
{
    __shared__ __align__(16) float qs[32 * 132];
    int ns = blockIdx.x, b = blockIdx.y;
    int n0 = ns * (HW_ / NS_);
    const float* q = y + (size_t)b * C_ * HW_;
    int tid = threadIdx.x;
    int td = tid & 15;
    int tc = tid >> 4;
    int c0 = tc * 8, d0 = td * 8;

    float acc[64];
    #pragma unroll
    for (int i = 0; i < 64; ++i) acc[i] = 0.f;

    for (int nb = 0; nb < (HW_ / NS_) / 32; ++nb) {
        __syncthreads();
        for (int idx = tid; idx < C_ * 32; idx += 256) {
            int c = idx >> 5;
            int nn = idx & 31;
            qs[nn * 132 + c] = q[(size_t)c * HW_ + n0 + nb * 32 + nn];
        }
        __syncthreads();
        for (int nn = 0; nn < 32; ++nn) {
            const float4* ap = (const float4*)&qs[nn * 132 + c0];
            const float4* bp = (const float4*)&qs[nn * 132 + d0];
            float4 a01 = ap[0], a23 = ap[1];
            float4 b01 = bp[0], b23 = bp[1];
            float av[8] = {a01.x, a01.y, a01.z, a01.w, a23.x, a23.y, a23.z, a23.w};
            float bv[8] = {b01.x, b01.y, b01.z, b01.w, b23.x, b23.y, b23.z, b23.w};
            #pragma unroll
            for (int i = 0; i < 8; ++i)
                #pragma unroll
                for (int j = 0; j < 8; ++j)
                    acc[i * 8 + j] = fmaf(av[i], bv[j], acc[i * 8 + j]);
        }
    }
    float* dst = simp + (size_t)(ns * B_ + b) * C_ * C_;
    #pragma unroll
    for (int i = 0; i < 8; ++i)
        #pragma unroll
        for (int j = 0; j < 8; ++j)
            dst[(c0 + i) * C_ + (d0 + j)] = acc[i * 8 + j];
}

// ---------------------------------------------------------------------------
// Kernel 5: reduce + softmax(-sim) (unchanged)
// ---------------------------------------------------------------------------
__global__ __launch_bounds__(128) void softmax_kernel(
    const float* __restrict__ simp, float* __restrict__ P)
{
    int bc = blockIdx.x;
    int b = bc / C_;
    int d = threadIdx.x;
    float s = 0.f;
    for (int ns = 0; ns < NS_; ++ns)
        s += simp[((size_t)(ns * B_ + b) * C_ + (bc % C_)) * C_ + d];
    float v = -s;
    float m = v;
    #pragma unroll
    for (int off = 32; off > 0; off >>= 1) m = fmaxf(m, __shfl_xor(m, off, 64));
    __shared__ float sm[2], ss[2];
    int wid = threadIdx.x >> 6;
    if ((threadIdx.x & 63) == 0) sm[wid] = m;
    __syncthreads();
    m = fmaxf(sm[0], sm[1]);
    float p = expf(v - m);
    float sum = p;
    #pragma unroll
    for (int off = 32; off > 0; off >>= 1) sum += __shfl_xor(sum, off, 64);
    if ((threadIdx.x & 63) == 0) ss[wid] = sum;
    __syncthreads();
    sum = ss[0] + ss[1];
    P[(size_t)bc * C_ + d] = p / sum;
}

// ---------------------------------------------------------------------------
// Kernel 6: feat = P @ y; out = gamma*feat + y (unchanged)
// ---------------------------------------------------------------------------
__global__ __launch_bounds__(256) void feat_kernel(
    const float* __restrict__ y, const float* __restrict__ P,
    const float* __restrict__ gamma, float* __restrict__ out)
{
    __shared__ __align__(16) float Ps[C_ * 32];
    int nc = blockIdx.x;
    int cg = blockIdx.y;
    int b  = blockIdx.z;
    int c0 = cg * 32;
    int tid = threadIdx.x;
    int n = nc * 256 + tid;

    for (int idx = tid; idx < C_ * 32; idx += 256) {
        int d = idx >> 5;
        int i = idx & 31;
        Ps[idx] = P[((size_t)b * C_ + c0 + i) * C_ + d];
    }
    __syncthreads();

    float acc[32];
    #pragma unroll
    for (int i = 0; i < 32; ++i) acc[i] = 0.f;
    const float* yb = y + (size_t)b * C_ * HW_;
    #pragma unroll 4
    for (int d = 0; d < C_; ++d) {
        float v = yb[(size_t)d * HW_ + n];
        const float4* pp = (const float4*)&Ps[d * 32];
        #pragma unroll
        for (int q4 = 0; q4 < 8; ++q4) {
            float4 w4 = pp[q4];
            acc[q4 * 4 + 0] = fmaf(w4.x, v, acc[q4 * 4 + 0]);
            acc[q4 * 4 + 1] = fmaf(w4.y, v, acc[q4 * 4 + 1]);
            acc[q4 * 4 + 2] = fmaf(w4.z, v, acc[q4 * 4 + 2]);
            acc[q4 * 4 + 3] = fmaf(w4.w, v, acc[q4 * 4 + 3]);
        }
    }
    float g = gamma[0];
    #pragma unroll
    for (int i = 0; i < 32; ++i) {
        size_t o = ((size_t)b * C_ + c0 + i) * HW_ + n;
        out[o] = g * acc[i] + y[o];
    }
}

// ---------------------------------------------------------------------------
extern "C" void kernel_launch(void* const* d_in, const int* in_sizes, int n_in,
                              void* d_out, int out_size, void* d_ws, size_t ws_size,
                              hipStream_t stream)
{
    const float* x1       = (const float*)d_in[0];
    const float* x2       = (const float*)d_in[1];
    const float* se_w1    = (const float*)d_in[2];
    const float* se_w2    = (const float*)d_in[3];
    const float* conv_w   = (const float*)d_in[4];
    const float* bn_gamma = (const float*)d_in[5];
    const float* bn_beta  = (const float*)d_in[6];
    const float* bn_mean  = (const float*)d_in[7];
    const float* bn_var   = (const float*)d_in[8];
    const float* gamma    = (const float*)d_in[9];
    float* out = (float*)d_out;

    char* ws = (char*)d_ws;
    const size_t xs_per_b = (size_t)H_ * W_ * C2_ * sizeof(f16);   // 8,388,608
    const size_t Y_OFF    = 1048576;                               // y: 64 MB
    const size_t XS_OFF   = Y_OFF + (size_t)B_ * C_ * HW_ * 4;     // 68,157,440
    const size_t SIMP_SZ  = (size_t)NS_ * B_ * C_ * C_ * 4;        // 16,777,216
    const size_t P_SZ     = (size_t)B_ * C_ * C_ * 4;              // 524,288

    float* avg  = (float*)(ws);            // 8 KB
    float* se   = (float*)(ws + 8192);     // 8 KB
    float* y    = (float*)(ws + Y_OFF);

    // choose batch-group size G by available workspace
    int G = 0;
    if      (ws_size >= XS_OFF + 8 * xs_per_b) G = 8;
    else if (ws_size >= XS_OFF + 4 * xs_per_b) G = 4;
    else if (ws_size >= XS_OFF + SIMP_SZ + P_SZ) G = 2;

    if (G > 0) {
        f16*   wt   = (f16*)(ws + 16384);          // 589,824 B
        f16*   xs   = (f16*)(ws + XS_OFF);
        float* simp = (float*)(ws + XS_OFF);       // aliases xs (used after conv)
        float* P    = (float*)(ws + XS_OFF + SIMP_SZ);

        wt_build_kernel<<<dim3(1152), 256, 0, stream>>>(conv_w, wt);
        avgpool_kernel<<<dim3(B_ * C2_), 256, 0, stream>>>(x1, x2, avg);
        se_mlp_kernel<<<dim3(1), 256, 0, stream>>>(avg, se_w1, se_w2, se);
        for (int g = 0; g < B_ / G; ++g) {
            xs_build_kernel<<<dim3(H_, G), 256, 0, stream>>>(x1, x2, se, xs, g * G);
            conv_mfma_kernel<<<dim3(H_, G), 256, 0, stream>>>(
                xs, wt, bn_gamma, bn_beta, bn_mean, bn_var, y, g * G);
        }
        sim_kernel<<<dim3(NS_, B_), 256, 0, stream>>>(y, simp);
        softmax_kernel<<<dim3(B_ * C_), 128, 0, stream>>>(simp, P);
        feat_kernel<<<dim3(64, 4, B_), 256, 0, stream>>>(y, P, gamma, out);
    } else {
        // round-1 fallback layout (84.9 MB, known good)
        float* P    = (float*)(ws + 16384);
        float* simp = (float*)(ws + XS_OFF);
        avgpool_kernel<<<dim3(B_ * C2_), 256, 0, stream>>>(x1, x2, avg);
        se_mlp_kernel<<<dim3(1), 256, 0, stream>>>(avg, se_w1, se_w2, se);
        conv_kernel<<<dim3(16, 8, B_), 256, 0, stream>>>(x1, x2, se, conv_w,
                                                         bn_gamma, bn_beta, bn_mean,
                                                         bn_var, y);
        sim_kernel<<<dim3(NS_, B_), 256, 0, stream>>>(y, simp);
        softmax_kernel<<<dim3(B_ * C_), 128, 0, stream>>>(simp, P);
        feat_kernel<<<dim3(64, 4, B_), 256, 0, stream>>>(y, P, gamma, out);
    }
}

// Round 3
// 405.118 us; speedup vs baseline: 4.8653x; 1.3491x over previous
//
#include <hip/hip_runtime.h>
#include <math.h>

// Problem constants
#define B_   8
#define C_   128
#define C2_  256
#define H_   128
#define W_   128
#define HW_  16384
#define CR_  32
#define EPS_ 1e-5f
#define NS_  32     // n-splits for sim partial sums

typedef _Float16 f16;
typedef f16 f16x8 __attribute__((ext_vector_type(8)));
typedef f16 f16x4 __attribute__((ext_vector_type(4)));
typedef float f32x4 __attribute__((ext_vector_type(4)));

// ---------------------------------------------------------------------------
// Kernel 1: prep — fused (avgpool partial sums) + (NHWC fp16 repack, UNscaled)
// Block=(h,b). LDS transpose with XOR swizzle (verified in R2).
// avg_sums must be zeroed before launch (hipMemsetAsync).
// ---------------------------------------------------------------------------
__global__ __launch_bounds__(256) void prep_kernel(
    const float* __restrict__ x1, const float* __restrict__ x2,
    float* __restrict__ avg_sums, f16* __restrict__ xs)
{
    __shared__ f16 T[W_ * 136];
    __shared__ float part[C2_];
    int h = blockIdx.x, b = blockIdx.y;
    int tid = threadIdx.x;
    part[tid] = 0.f;
    f16* out = xs + ((size_t)b * H_ + h) * W_ * C2_;
    for (int p = 0; p < 2; ++p) {
        const float* src = p ? x2 : x1;
        __syncthreads();
        for (int idx = tid; idx < C_ * 32; idx += 256) {
            int c = idx >> 5, w4 = (idx & 31) << 2;
            const float4 v = *(const float4*)&src[(((size_t)b * C_ + c) * H_ + h) * W_ + w4];
            // avg partial: sum over the 32 lanes sharing this c (lanes 0-31 / 32-63)
            float s = v.x + v.y + v.z + v.w;
            s += __shfl_xor(s, 1, 64);  s += __shfl_xor(s, 2, 64);
            s += __shfl_xor(s, 4, 64);  s += __shfl_xor(s, 8, 64);
            s += __shfl_xor(s, 16, 64);
            if ((tid & 31) == 0) part[p * C_ + c] = s;   // unique (wave,iter)->c
            int cs = c ^ (8 * ((idx & 31) & 15));
            T[(w4 + 0) * 136 + cs] = (f16)v.x;
            T[(w4 + 1) * 136 + cs] = (f16)v.y;
            T[(w4 + 2) * 136 + cs] = (f16)v.z;
            T[(w4 + 3) * 136 + cs] = (f16)v.w;
        }
        __syncthreads();
        for (int u = tid; u < W_ * 16; u += 256) {
            int w = u >> 4, o = u & 15;
            f16x8 v = *(const f16x8*)&T[w * 136 + ((o * 8) ^ (8 * ((w >> 2) & 15)))];
            *(f16x8*)&out[w * C2_ + p * C_ + o * 8] = v;
        }
    }
    __syncthreads();
    atomicAdd(&avg_sums[b * C2_ + tid], part[tid]);
}

// ---------------------------------------------------------------------------
// Kernel 2: SE MLP (avg_sums are raw sums; scale by 1/HW here)
// ---------------------------------------------------------------------------
__global__ __launch_bounds__(256) void se_mlp_kernel(
    const float* __restrict__ avg_sums, const float* __restrict__ w1,
    const float* __restrict__ w2, float* __restrict__ se)
{
    __shared__ float s_avg[B_ * C2_];
    __shared__ float s_h[B_ * CR_];
    for (int i = threadIdx.x; i < B_ * C2_; i += 256)
        s_avg[i] = avg_sums[i] * (1.f / (float)HW_);
    __syncthreads();
    {
        int i = threadIdx.x;            // exactly B*CR = 256
        int b = i / CR_, j = i % CR_;
        float s = 0.f;
        for (int k = 0; k < C2_; ++k) s += s_avg[b * C2_ + k] * w1[j * C2_ + k];
        s_h[i] = fmaxf(s, 0.f);
    }
    __syncthreads();
    for (int i = threadIdx.x; i < B_ * C2_; i += 256) {
        int b = i / C2_, c = i % C2_;
        float s = 0.f;
        #pragma unroll
        for (int j = 0; j < CR_; ++j) s += s_h[b * CR_ + j] * w2[c * CR_ + j];
        se[i] = 1.f / (1.f + expf(-s));
    }
}

// ---------------------------------------------------------------------------
// Kernel 3: weight repack  conv_w[co][2C][3][3] fp32 -> wt[9][8][128][32] fp16
// ---------------------------------------------------------------------------
__global__ __launch_bounds__(256) void wt_build_kernel(
    const float* __restrict__ conv_w, f16* __restrict__ wt)
{
    int idx = blockIdx.x * 256 + threadIdx.x;   // < 9*8*128*32 = 294912 exact
    int ci = idx & 31;
    int co = (idx >> 5) & 127;
    int cc = (idx >> 12) & 7;
    int t  = idx >> 15;
    wt[idx] = (f16)conv_w[((size_t)co * C2_ + cc * 32 + ci) * 9 + t];
}

// ---------------------------------------------------------------------------
// Kernel 4: conv implicit GEMM, fp16 MFMA, distance-2 weight prefetch.
// Block=(h,b): M=128 co x N=128 w, K=8 chunks x 9 taps x 32ci.
// SE scale applied to X during LDS staging (pk_mul_f16).
// Epilogue: BN+ReLU -> yh [b][c][n] fp16 (for sim) + yt [b][n][c] fp16 (for feat).
// ---------------------------------------------------------------------------
#define XROW 130
#define XPAD 40

__global__ __launch_bounds__(256, 3) void conv_mfma_kernel(
    const f16* __restrict__ xs, const f16* __restrict__ wt,
    const float* __restrict__ se,
    const float* __restrict__ bn_gamma, const float* __restrict__ bn_beta,
    const float* __restrict__ bn_mean, const float* __restrict__ bn_var,
    f16* __restrict__ yh, f16* __restrict__ yt)
{
    __shared__ f16 Xs[3 * XROW * XPAD];                    // 31200 B
    __shared__ __align__(16) f16 seh[C2_];                 // 512 B
    int h = blockIdx.x, b = blockIdx.y;
    int tid = threadIdx.x;
    int wave = tid >> 6, lane = tid & 63;
    int wm = wave >> 1, wn = wave & 1;
    int lr = lane & 15, kg = lane >> 4;
    const f16* xsb = xs + (size_t)b * ((size_t)H_ * W_ * C2_);

    seh[tid] = (f16)se[b * C2_ + tid];

    f32x4 acc[4][4];
    #pragma unroll
    for (int i = 0; i < 4; ++i)
        #pragma unroll
        for (int j = 0; j < 4; ++j)
            #pragma unroll
            for (int r = 0; r < 4; ++r) acc[i][j][r] = 0.f;

    auto ldaf = [&](int cc, int t, f16x8* dst) {
        const f16* wb = wt + ((size_t)(t * 8 + cc) * C_) * 32;
        #pragma unroll
        for (int i = 0; i < 4; ++i)
            dst[i] = *(const f16x8*)&wb[(wm * 64 + i * 16 + lr) * 32 + kg * 8];
    };

    f16x8 af3[3][4];
    ldaf(0, 0, af3[0]);
    ldaf(0, 1, af3[1]);

    for (int cc = 0; cc < 8; ++cc) {
        __syncthreads();
        // stage 32ci x 3rows x 130cols (zero-pad borders), SE-scaled
        for (int u = tid; u < 3 * XROW * 4; u += 256) {
            int r = u / (XROW * 4);
            int rem = u - r * (XROW * 4);
            int col = rem >> 2, q = rem & 3;
            int gh = h + r - 1, gw = col - 1;
            f16x8 v;
            #pragma unroll
            for (int z = 0; z < 8; ++z) v[z] = (f16)0.f;
            if ((unsigned)gh < (unsigned)H_ && (unsigned)gw < (unsigned)W_) {
                v = *(const f16x8*)&xsb[((size_t)(gh * W_ + gw)) * C2_ + cc * 32 + q * 8];
                f16x8 sv = *(const f16x8*)&seh[cc * 32 + q * 8];
                v = v * sv;
            }
            *(f16x8*)&Xs[(r * XROW + col) * XPAD + q * 8] = v;
        }
        __syncthreads();
        #pragma unroll
        for (int t = 0; t < 9; ++t) {
            const int dh = t / 3, dw = t % 3;
            // distance-2 prefetch (rotating 3-buffer); crosses chunk boundary
            {
                int pt = t + 2, pcc = cc;
                if (pt >= 9) { pt -= 9; ++pcc; }
                if (pcc < 8) ldaf(pcc, pt, af3[(t + 2) % 3]);
            }
            f16x8 bf[4];
            #pragma unroll
            for (int j = 0; j < 4; ++j)
                bf[j] = *(const f16x8*)&Xs[(dh * XROW + (wn * 64 + j * 16 + lr + dw)) * XPAD + kg * 8];
            const f16x8* af = af3[t % 3];
            #pragma unroll
            for (int i = 0; i < 4; ++i)
                #pragma unroll
                for (int j = 0; j < 4; ++j)
                    acc[i][j] = __builtin_amdgcn_mfma_f32_16x16x32_f16(af[i], bf[j], acc[i][j], 0, 0, 0);
        }
    }
    // epilogue: BN+ReLU; D layout col=lane&15 (n), row=kg*4+r (c)
    #pragma unroll
    for (int i = 0; i < 4; ++i) {
        int cb = wm * 64 + i * 16 + kg * 4;
        float inv[4], add[4];
        #pragma unroll
        for (int r = 0; r < 4; ++r) {
            int c = cb + r;
            inv[r] = bn_gamma[c] * rsqrtf(bn_var[c] + EPS_);
            add[r] = bn_beta[c] - bn_mean[c] * inv[r];
        }
        #pragma unroll
        for (int j = 0; j < 4; ++j) {
            int n = wn * 64 + j * 16 + lr;
            f16x4 tv;
            #pragma unroll
            for (int r = 0; r < 4; ++r) {
                float v = fmaxf(acc[i][j][r] * inv[r] + add[r], 0.f);
                tv[r] = (f16)v;
                yh[((size_t)b * C_ + cb + r) * HW_ + h * W_ + n] = (f16)v;
            }
            *(f16x4*)&yt[((size_t)b * HW_ + h * W_ + n) * C_ + cb] = tv;
        }
    }
}

// ---------------------------------------------------------------------------
// Kernel 5: sim partials via MFMA.  simp[ns][b][c][d] = sum_slice yh_c . yh_d
// Block=(ns,b), 512 threads = 8 waves (2 M-halves x 4 N-quarters).
// A and B fragments load directly from global yh (K=n contiguous).
// ---------------------------------------------------------------------------
__global__ __launch_bounds__(512) void sim_mfma_kernel(
    const f16* __restrict__ yh, float* __restrict__ simp)
{
    int ns = blockIdx.x, b = blockIdx.y;
    int tid = threadIdx.x, wave = tid >> 6, lane = tid & 63;
    int wm = wave >> 2, wn = wave & 3;
    int lr = lane & 15, kg = lane >> 4;
    const f16* Y = yh + (size_t)b * C_ * HW_;
    int n0 = ns * (HW_ / NS_);                 // 512-wide slice

    f32x4 acc[4][2];
    #pragma unroll
    for (int i = 0; i < 4; ++i)
        #pragma unroll
        for (int j = 0; j < 2; ++j)
            #pragma unroll
            for (int r = 0; r < 4; ++r) acc[i][j][r] = 0.f;

    for (int kk = 0; kk < 16; ++kk) {
        int k = n0 + kk * 32 + kg * 8;
        f16x8 af[4], bf[2];
        #pragma unroll
        for (int i = 0; i < 4; ++i)
            af[i] = *(const f16x8*)&Y[(size_t)(wm * 64 + i * 16 + lr) * HW_ + k];
        #pragma unroll
        for (int j = 0; j < 2; ++j)
            bf[j] = *(const f16x8*)&Y[(size_t)(wn * 32 + j * 16 + lr) * HW_ + k];
        #pragma unroll
        for (int i = 0; i < 4; ++i)
            #pragma unroll
            for (int j = 0; j < 2; ++j)
                acc[i][j] = __builtin_amdgcn_mfma_f32_16x16x32_f16(af[i], bf[j], acc[i][j], 0, 0, 0);
    }
    float* dst = simp + (size_t)(ns * B_ + b) * C_ * C_;
    #pragma unroll
    for (int i = 0; i < 4; ++i)
        #pragma unroll
        for (int j = 0; j < 2; ++j)
            #pragma unroll
            for (int r = 0; r < 4; ++r)
                dst[(wm * 64 + i * 16 + kg * 4 + r) * C_ + wn * 32 + j * 16 + lr] = acc[i][j][r];
}

// ---------------------------------------------------------------------------
// Kernel 6: reduce partials + softmax(-sim) -> Ph fp16 [b][c][d]
// ---------------------------------------------------------------------------
__global__ __launch_bounds__(128) void softmax_kernel(
    const float* __restrict__ simp, f16* __restrict__ Ph)
{
    int bc = blockIdx.x;
    int b = bc / C_;
    int d = threadIdx.x;
    float s = 0.f;
    for (int ns = 0; ns < NS_; ++ns)
        s += simp[((size_t)(ns * B_ + b) * C_ + (bc % C_)) * C_ + d];
    float v = -s;
    float m = v;
    #pragma unroll
    for (int off = 32; off > 0; off >>= 1) m = fmaxf(m, __shfl_xor(m, off, 64));
    __shared__ float sm[2], ss[2];
    int wid = threadIdx.x >> 6;
    if ((threadIdx.x & 63) == 0) sm[wid] = m;
    __syncthreads();
    m = fmaxf(sm[0], sm[1]);
    float p = expf(v - m);
    float sum = p;
    #pragma unroll
    for (int off = 32; off > 0; off >>= 1) sum += __shfl_xor(sum, off, 64);
    if ((threadIdx.x & 63) == 0) ss[wid] = sum;
    __syncthreads();
    sum = ss[0] + ss[1];
    Ph[(size_t)bc * C_ + d] = (f16)(p / sum);
}

// ---------------------------------------------------------------------------
// Kernel 7: feat = P @ y via MFMA; out = gamma*feat + y (residual from yt fp16)
// Block=(n-tile, b): M=128 c x N=128 n x K=128 d. No LDS; P and yt are
// K-contiguous so all fragments are direct global b128 loads (L2-hot).
// ---------------------------------------------------------------------------
__global__ __launch_bounds__(256) void feat_mfma_kernel(
    const f16* __restrict__ Ph, const f16* __restrict__ yt,
    const float* __restrict__ gamma, float* __restrict__ out)
{
    int nt = blockIdx.x, b = blockIdx.y;
    int tid = threadIdx.x, wave = tid >> 6, lane = tid & 63;
    int wm = wave >> 1, wn = wave & 1;
    int lr = lane & 15, kg = lane >> 4;
    int n0 = nt * 128;
    const f16* Pb = Ph + (size_t)b * C_ * C_;
    const f16* Yt = yt + (size_t)b * HW_ * C_;

    f32x4 acc[4][4];
    #pragma unroll
    for (int i = 0; i < 4; ++i)
        #pragma unroll
        for (int j = 0; j < 4; ++j)
            #pragma unroll
            for (int r = 0; r < 4; ++r) acc[i][j][r] = 0.f;

    #pragma unroll
    for (int kk = 0; kk < 4; ++kk) {
        int k = kk * 32 + kg * 8;
        f16x8 af[4], bf[4];
        #pragma unroll
        for (int i = 0; i < 4; ++i)
            af[i] = *(const f16x8*)&Pb[(wm * 64 + i * 16 + lr) * C_ + k];
        #pragma unroll
        for (int j = 0; j < 4; ++j)
            bf[j] = *(const f16x8*)&Yt[(size_t)(n0 + wn * 64 + j * 16 + lr) * C_ + k];
        #pragma unroll
        for (int i = 0; i < 4; ++i)
            #pragma unroll
            for (int j = 0; j < 4; ++j)
                acc[i][j] = __builtin_amdgcn_mfma_f32_16x16x32_f16(af[i], bf[j], acc[i][j], 0, 0, 0);
    }
    float g = gamma[0];
    #pragma unroll
    for (int i = 0; i < 4; ++i) {
        int cb = wm * 64 + i * 16 + kg * 4;
        #pragma unroll
        for (int j = 0; j < 4; ++j) {
            int n = n0 + wn * 64 + j * 16 + lr;
            f16x4 rv = *(const f16x4*)&Yt[(size_t)n * C_ + cb];
            #pragma unroll
            for (int r = 0; r < 4; ++r)
                out[((size_t)b * C_ + cb + r) * HW_ + n] = g * acc[i][j][r] + (float)rv[r];
        }
    }
}

// ---------------------------------------------------------------------------
extern "C" void kernel_launch(void* const* d_in, const int* in_sizes, int n_in,
                              void* d_out, int out_size, void* d_ws, size_t ws_size,
                              hipStream_t stream)
{
    const float* x1       = (const float*)d_in[0];
    const float* x2       = (const float*)d_in[1];
    const float* se_w1    = (const float*)d_in[2];
    const float* se_w2    = (const float*)d_in[3];
    const float* conv_w   = (const float*)d_in[4];
    const float* bn_gamma = (const float*)d_in[5];
    const float* bn_beta  = (const float*)d_in[6];
    const float* bn_mean  = (const float*)d_in[7];
    const float* bn_var   = (const float*)d_in[8];
    const float* gamma    = (const float*)d_in[9];
    float* out = (float*)d_out;

    // Workspace layout — total 135,266,304 B (== R2's proven G=8 footprint)
    char* ws = (char*)d_ws;
    float* avg  = (float*)(ws);                      //       0 +     8 KB
    float* se   = (float*)(ws + 8192);               //    8192 +     8 KB
    f16*   Ph   = (f16*)  (ws + 16384);              //   16384 +   256 KB
    f16*   wt   = (f16*)  (ws + 278528);             //  278528 +   576 KB
    f16*   xs   = (f16*)  (ws + 1048576);            // 1 MB    +    64 MB
    float* simp = (float*)(ws + 1048576);            // aliases xs (post-conv)
    f16*   yh   = (f16*)  (ws + 68157440);           //         +    32 MB
    f16*   yt   = (f16*)  (ws + 101711872);          //         +    32 MB

    hipMemsetAsync(avg, 0, B_ * C2_ * sizeof(float), stream);
    prep_kernel<<<dim3(H_, B_), 256, 0, stream>>>(x1, x2, avg, xs);
    se_mlp_kernel<<<dim3(1), 256, 0, stream>>>(avg, se_w1, se_w2, se);
    wt_build_kernel<<<dim3(1152), 256, 0, stream>>>(conv_w, wt);
    conv_mfma_kernel<<<dim3(H_, B_), 256, 0, stream>>>(
        xs, wt, se, bn_gamma, bn_beta, bn_mean, bn_var, yh, yt);
    sim_mfma_kernel<<<dim3(NS_, B_), 512, 0, stream>>>(yh, simp);
    softmax_kernel<<<dim3(B_ * C_), 128, 0, stream>>>(simp, Ph);
    feat_mfma_kernel<<<dim3(HW_ / 128, B_), 256, 0, stream>>>(Ph, yt, gamma, out);
}

// Round 4
// 388.996 us; speedup vs baseline: 5.0670x; 1.0414x over previous
//
#include <hip/hip_runtime.h>
#include <math.h>

// Problem constants
#define B_   8
#define C_   128
#define C2_  256
#define H_   128
#define W_   128
#define HW_  16384
#define CR_  32
#define EPS_ 1e-5f
#define NS_  32     // n-splits for sim partial sums

typedef _Float16 f16;
typedef f16 f16x8 __attribute__((ext_vector_type(8)));
typedef f16 f16x4 __attribute__((ext_vector_type(4)));
typedef float f32x4 __attribute__((ext_vector_type(4)));

// ---------------------------------------------------------------------------
// Kernel 1: prep — fused (avgpool partial sums) + (NHWC fp16 repack, UNscaled)
// Block=(h,b). LDS transpose with XOR swizzle (verified R2/R3).
// ---------------------------------------------------------------------------
__global__ __launch_bounds__(256) void prep_kernel(
    const float* __restrict__ x1, const float* __restrict__ x2,
    float* __restrict__ avg_sums, f16* __restrict__ xs)
{
    __shared__ f16 T[W_ * 136];
    __shared__ float part[C2_];
    int h = blockIdx.x, b = blockIdx.y;
    int tid = threadIdx.x;
    part[tid] = 0.f;
    f16* out = xs + ((size_t)b * H_ + h) * W_ * C2_;
    for (int p = 0; p < 2; ++p) {
        const float* src = p ? x2 : x1;
        __syncthreads();
        for (int idx = tid; idx < C_ * 32; idx += 256) {
            int c = idx >> 5, w4 = (idx & 31) << 2;
            const float4 v = *(const float4*)&src[(((size_t)b * C_ + c) * H_ + h) * W_ + w4];
            float s = v.x + v.y + v.z + v.w;
            s += __shfl_xor(s, 1, 64);  s += __shfl_xor(s, 2, 64);
            s += __shfl_xor(s, 4, 64);  s += __shfl_xor(s, 8, 64);
            s += __shfl_xor(s, 16, 64);
            if ((tid & 31) == 0) part[p * C_ + c] = s;
            int cs = c ^ (8 * ((idx & 31) & 15));
            T[(w4 + 0) * 136 + cs] = (f16)v.x;
            T[(w4 + 1) * 136 + cs] = (f16)v.y;
            T[(w4 + 2) * 136 + cs] = (f16)v.z;
            T[(w4 + 3) * 136 + cs] = (f16)v.w;
        }
        __syncthreads();
        for (int u = tid; u < W_ * 16; u += 256) {
            int w = u >> 4, o = u & 15;
            f16x8 v = *(const f16x8*)&T[w * 136 + ((o * 8) ^ (8 * ((w >> 2) & 15)))];
            *(f16x8*)&out[w * C2_ + p * C_ + o * 8] = v;
        }
    }
    __syncthreads();
    atomicAdd(&avg_sums[b * C2_ + tid], part[tid]);
}

// ---------------------------------------------------------------------------
// Kernel 2: SE MLP
// ---------------------------------------------------------------------------
__global__ __launch_bounds__(256) void se_mlp_kernel(
    const float* __restrict__ avg_sums, const float* __restrict__ w1,
    const float* __restrict__ w2, float* __restrict__ se)
{
    __shared__ float s_avg[B_ * C2_];
    __shared__ float s_h[B_ * CR_];
    for (int i = threadIdx.x; i < B_ * C2_; i += 256)
        s_avg[i] = avg_sums[i] * (1.f / (float)HW_);
    __syncthreads();
    {
        int i = threadIdx.x;
        int b = i / CR_, j = i % CR_;
        float s = 0.f;
        for (int k = 0; k < C2_; ++k) s += s_avg[b * C2_ + k] * w1[j * C2_ + k];
        s_h[i] = fmaxf(s, 0.f);
    }
    __syncthreads();
    for (int i = threadIdx.x; i < B_ * C2_; i += 256) {
        int b = i / C2_, c = i % C2_;
        float s = 0.f;
        #pragma unroll
        for (int j = 0; j < CR_; ++j) s += s_h[b * CR_ + j] * w2[c * CR_ + j];
        se[i] = 1.f / (1.f + expf(-s));
    }
}

// ---------------------------------------------------------------------------
// Kernel 3: weight repack  conv_w[co][2C][3][3] fp32 -> wt[9][8][128][32] fp16
// ---------------------------------------------------------------------------
__global__ __launch_bounds__(256) void wt_build_kernel(
    const float* __restrict__ conv_w, f16* __restrict__ wt)
{
    int idx = blockIdx.x * 256 + threadIdx.x;
    int ci = idx & 31;
    int co = (idx >> 5) & 127;
    int cc = (idx >> 12) & 7;
    int t  = idx >> 15;
    wt[idx] = (f16)conv_w[((size_t)co * C2_ + cc * 32 + ci) * 9 + t];
}

// ---------------------------------------------------------------------------
// Kernel 4: conv implicit GEMM, fp16 MFMA.
// Block = 2 output rows x co128 x n128. 4 waves = n-quarters; each wave
// M=128(co) x N=32(n) x 2 rows. af (weights) in regs, loaded once per
// (chunk,tap), shared by all waves via L1. bf from conflict-free LDS.
// Epilogue: BN+ReLU -> yh (NCHW f16) + LDS-transposed coalesced yt (NHWC f16).
// ---------------------------------------------------------------------------
__global__ __launch_bounds__(256, 2) void conv_mfma_kernel(
    const f16* __restrict__ xs, const f16* __restrict__ wt,
    const float* __restrict__ se,
    const float* __restrict__ bn_gamma, const float* __restrict__ bn_beta,
    const float* __restrict__ bn_mean, const float* __restrict__ bn_var,
    f16* __restrict__ yh, f16* __restrict__ yt)
{
    // Xs: staging tile, 4 rows x 130 cols x 32 ci as 16B units [(r*4+q)*132+col]
    //     (bank = 16(q&1)+4col -> conflict-free fragment reads)
    // reused in epilogue as T[n][136] for the yt transpose (needs 17408 f16)
    __shared__ f16 Xs[17408];                              // 34816 B
    __shared__ __align__(16) f16 seh[C2_];
    int h0 = blockIdx.x * 2, b = blockIdx.y;
    int tid = threadIdx.x;
    int wave = tid >> 6, lane = tid & 63;
    int wn = wave;                       // n-quarter
    int lr = lane & 15, kg = lane >> 4;
    const f16* xsb = xs + (size_t)b * ((size_t)H_ * W_ * C2_);

    seh[tid] = (f16)se[b * C2_ + tid];

    f32x4 acc[2][8][2];
    #pragma unroll
    for (int o = 0; o < 2; ++o)
        #pragma unroll
        for (int i = 0; i < 8; ++i)
            #pragma unroll
            for (int j = 0; j < 2; ++j)
                #pragma unroll
                for (int r = 0; r < 4; ++r) acc[o][i][j][r] = 0.f;

    f16x8 afb[2][8];
    auto ldaf = [&](int cc, int t, f16x8* dst) {
        const f16* wb = wt + ((size_t)(t * 8 + cc) * C_) * 32;
        #pragma unroll
        for (int i = 0; i < 8; ++i)
            dst[i] = *(const f16x8*)&wb[(i * 16 + lr) * 32 + kg * 8];
    };

    for (int cc = 0; cc < 8; ++cc) {
        __syncthreads();
        ldaf(cc, 0, afb[0]);   // overlaps with staging below
        // stage 4 input rows (h0-1 .. h0+2) x 130 cols x 32 ci, SE-scaled
        for (int u = tid; u < 4 * 130 * 4; u += 256) {
            int r = u / 520;
            int rem = u - r * 520;
            int col = rem >> 2, q = rem & 3;
            int gh = h0 - 1 + r, gw = col - 1;
            f16x8 v;
            #pragma unroll
            for (int z = 0; z < 8; ++z) v[z] = (f16)0.f;
            if ((unsigned)gh < (unsigned)H_ && (unsigned)gw < (unsigned)W_) {
                v = *(const f16x8*)&xsb[((size_t)(gh * W_ + gw)) * C2_ + cc * 32 + q * 8];
                f16x8 sv = *(const f16x8*)&seh[cc * 32 + q * 8];
                v = v * sv;
            }
            *(f16x8*)&Xs[((r * 4 + q) * 132 + col) * 8] = v;
        }
        __syncthreads();
        #pragma unroll
        for (int t = 0; t < 9; ++t) {
            const int dh = t / 3, dw = t % 3;
            if (t < 8) ldaf(cc, t + 1, afb[(t + 1) & 1]);   // prefetch next tap
            const f16x8* af = afb[t & 1];
            #pragma unroll
            for (int o = 0; o < 2; ++o) {
                int r = o + dh;                             // input row index
                f16x8 bf[2];
                #pragma unroll
                for (int j = 0; j < 2; ++j)
                    bf[j] = *(const f16x8*)&Xs[((r * 4 + kg) * 132 +
                                (wn * 32 + j * 16 + lr + dw)) * 8];
                #pragma unroll
                for (int i = 0; i < 8; ++i)
                    #pragma unroll
                    for (int j = 0; j < 2; ++j)
                        acc[o][i][j] = __builtin_amdgcn_mfma_f32_16x16x32_f16(
                            af[i], bf[j], acc[o][i][j], 0, 0, 0);
            }
        }
    }
    // epilogue: BN+ReLU; D layout col(lane&15)=n, row=kg*4+r(+16i)=c.
    // yh direct (2B coalesced); yt via LDS transpose (16B coalesced stores).
    #pragma unroll
    for (int o = 0; o < 2; ++o) {
        __syncthreads();    // Xs free (or previous o's T consumed)
        #pragma unroll
        for (int i = 0; i < 8; ++i) {
            int cb = i * 16 + kg * 4;
            float inv[4], add[4];
            #pragma unroll
            for (int r = 0; r < 4; ++r) {
                int c = cb + r;
                inv[r] = bn_gamma[c] * rsqrtf(bn_var[c] + EPS_);
                add[r] = bn_beta[c] - bn_mean[c] * inv[r];
            }
            #pragma unroll
            for (int j = 0; j < 2; ++j) {
                int n = wn * 32 + j * 16 + lr;
                f16x4 tv;
                #pragma unroll
                for (int r = 0; r < 4; ++r) {
                    float v = fmaxf(acc[o][i][j][r] * inv[r] + add[r], 0.f);
                    tv[r] = (f16)v;
                    yh[((size_t)b * C_ + cb + r) * HW_ + (h0 + o) * W_ + n] = (f16)v;
                }
                *(f16x4*)&Xs[n * 136 + cb] = tv;   // T[n][c]
            }
        }
        __syncthreads();
        for (int u = tid; u < 128 * 16; u += 256) {
            int n = u >> 4, o8 = u & 15;
            f16x8 v = *(const f16x8*)&Xs[n * 136 + o8 * 8];
            *(f16x8*)&yt[((size_t)b * HW_ + (h0 + o) * W_ + n) * C_ + o8 * 8] = v;
        }
    }
}

// ---------------------------------------------------------------------------
// Kernel 5: sim partials via MFMA (unchanged from R3)
// ---------------------------------------------------------------------------
__global__ __launch_bounds__(512) void sim_mfma_kernel(
    const f16* __restrict__ yh, float* __restrict__ simp)
{
    int ns = blockIdx.x, b = blockIdx.y;
    int tid = threadIdx.x, wave = tid >> 6, lane = tid & 63;
    int wm = wave >> 2, wn = wave & 3;
    int lr = lane & 15, kg = lane >> 4;
    const f16* Y = yh + (size_t)b * C_ * HW_;
    int n0 = ns * (HW_ / NS_);

    f32x4 acc[4][2];
    #pragma unroll
    for (int i = 0; i < 4; ++i)
        #pragma unroll
        for (int j = 0; j < 2; ++j)
            #pragma unroll
            for (int r = 0; r < 4; ++r) acc[i][j][r] = 0.f;

    for (int kk = 0; kk < 16; ++kk) {
        int k = n0 + kk * 32 + kg * 8;
        f16x8 af[4], bf[2];
        #pragma unroll
        for (int i = 0; i < 4; ++i)
            af[i] = *(const f16x8*)&Y[(size_t)(wm * 64 + i * 16 + lr) * HW_ + k];
        #pragma unroll
        for (int j = 0; j < 2; ++j)
            bf[j] = *(const f16x8*)&Y[(size_t)(wn * 32 + j * 16 + lr) * HW_ + k];
        #pragma unroll
        for (int i = 0; i < 4; ++i)
            #pragma unroll
            for (int j = 0; j < 2; ++j)
                acc[i][j] = __builtin_amdgcn_mfma_f32_16x16x32_f16(af[i], bf[j], acc[i][j], 0, 0, 0);
    }
    float* dst = simp + (size_t)(ns * B_ + b) * C_ * C_;
    #pragma unroll
    for (int i = 0; i < 4; ++i)
        #pragma unroll
        for (int j = 0; j < 2; ++j)
            #pragma unroll
            for (int r = 0; r < 4; ++r)
                dst[(wm * 64 + i * 16 + kg * 4 + r) * C_ + wn * 32 + j * 16 + lr] = acc[i][j][r];
}

// ---------------------------------------------------------------------------
// Kernel 6: reduce partials + softmax(-sim) -> Ph fp16 (unchanged)
// ---------------------------------------------------------------------------
__global__ __launch_bounds__(128) void softmax_kernel(
    const float* __restrict__ simp, f16* __restrict__ Ph)
{
    int bc = blockIdx.x;
    int b = bc / C_;
    int d = threadIdx.x;
    float s = 0.f;
    for (int ns = 0; ns < NS_; ++ns)
        s += simp[((size_t)(ns * B_ + b) * C_ + (bc % C_)) * C_ + d];
    float v = -s;
    float m = v;
    #pragma unroll
    for (int off = 32; off > 0; off >>= 1) m = fmaxf(m, __shfl_xor(m, off, 64));
    __shared__ float sm[2], ss[2];
    int wid = threadIdx.x >> 6;
    if ((threadIdx.x & 63) == 0) sm[wid] = m;
    __syncthreads();
    m = fmaxf(sm[0], sm[1]);
    float p = expf(v - m);
    float sum = p;
    #pragma unroll
    for (int off = 32; off > 0; off >>= 1) sum += __shfl_xor(sum, off, 64);
    if ((threadIdx.x & 63) == 0) ss[wid] = sum;
    __syncthreads();
    sum = ss[0] + ss[1];
    Ph[(size_t)bc * C_ + d] = (f16)(p / sum);
}

// ---------------------------------------------------------------------------
// Kernel 7: feat = P @ y via MFMA; out = gamma*feat + y
// Residual read from yh (coalesced 2B) instead of scattered Yt.
// ---------------------------------------------------------------------------
__global__ __launch_bounds__(256) void feat_mfma_kernel(
    const f16* __restrict__ Ph, const f16* __restrict__ yt,
    const f16* __restrict__ yh,
    const float* __restrict__ gamma, float* __restrict__ out)
{
    int nt = blockIdx.x, b = blockIdx.y;
    int tid = threadIdx.x, wave = tid >> 6, lane = tid & 63;
    int wm = wave >> 1, wn = wave & 1;
    int lr = lane & 15, kg = lane >> 4;
    int n0 = nt * 128;
    const f16* Pb = Ph + (size_t)b * C_ * C_;
    const f16* Yt = yt + (size_t)b * HW_ * C_;

    f32x4 acc[4][4];
    #pragma unroll
    for (int i = 0; i < 4; ++i)
        #pragma unroll
        for (int j = 0; j < 4; ++j)
            #pragma unroll
            for (int r = 0; r < 4; ++r) acc[i][j][r] = 0.f;

    #pragma unroll
    for (int kk = 0; kk < 4; ++kk) {
        int k = kk * 32 + kg * 8;
        f16x8 af[4], bf[4];
        #pragma unroll
        for (int i = 0; i < 4; ++i)
            af[i] = *(const f16x8*)&Pb[(wm * 64 + i * 16 + lr) * C_ + k];
        #pragma unroll
        for (int j = 0; j < 4; ++j)
            bf[j] = *(const f16x8*)&Yt[(size_t)(n0 + wn * 64 + j * 16 + lr) * C_ + k];
        #pragma unroll
        for (int i = 0; i < 4; ++i)
            #pragma unroll
            for (int j = 0; j < 4; ++j)
                acc[i][j] = __builtin_amdgcn_mfma_f32_16x16x32_f16(af[i], bf[j], acc[i][j], 0, 0, 0);
    }
    float g = gamma[0];
    #pragma unroll
    for (int i = 0; i < 4; ++i) {
        int cb = wm * 64 + i * 16 + kg * 4;
        #pragma unroll
        for (int j = 0; j < 4; ++j) {
            int n = n0 + wn * 64 + j * 16 + lr;
            #pragma unroll
            for (int r = 0; r < 4; ++r) {
                float res = (float)yh[((size_t)b * C_ + cb + r) * HW_ + n];
                out[((size_t)b * C_ + cb + r) * HW_ + n] = g * acc[i][j][r] + res;
            }
        }
    }
}

// ---------------------------------------------------------------------------
extern "C" void kernel_launch(void* const* d_in, const int* in_sizes, int n_in,
                              void* d_out, int out_size, void* d_ws, size_t ws_size,
                              hipStream_t stream)
{
    const float* x1       = (const float*)d_in[0];
    const float* x2       = (const float*)d_in[1];
    const float* se_w1    = (const float*)d_in[2];
    const float* se_w2    = (const float*)d_in[3];
    const float* conv_w   = (const float*)d_in[4];
    const float* bn_gamma = (const float*)d_in[5];
    const float* bn_beta  = (const float*)d_in[6];
    const float* bn_mean  = (const float*)d_in[7];
    const float* bn_var   = (const float*)d_in[8];
    const float* gamma    = (const float*)d_in[9];
    float* out = (float*)d_out;

    // Workspace layout — total 135,266,304 B (R2/R3-proven footprint)
    char* ws = (char*)d_ws;
    float* avg  = (float*)(ws);                      //       0 +     8 KB
    float* se   = (float*)(ws + 8192);               //    8192 +     8 KB
    f16*   Ph   = (f16*)  (ws + 16384);              //   16384 +   256 KB
    f16*   wt   = (f16*)  (ws + 278528);             //  278528 +   576 KB
    f16*   xs   = (f16*)  (ws + 1048576);            // 1 MB    +    64 MB
    float* simp = (float*)(ws + 1048576);            // aliases xs (post-conv)
    f16*   yh   = (f16*)  (ws + 68157440);           //         +    32 MB
    f16*   yt   = (f16*)  (ws + 101711872);          //         +    32 MB

    hipMemsetAsync(avg, 0, B_ * C2_ * sizeof(float), stream);
    prep_kernel<<<dim3(H_, B_), 256, 0, stream>>>(x1, x2, avg, xs);
    se_mlp_kernel<<<dim3(1), 256, 0, stream>>>(avg, se_w1, se_w2, se);
    wt_build_kernel<<<dim3(1152), 256, 0, stream>>>(conv_w, wt);
    conv_mfma_kernel<<<dim3(H_ / 2, B_), 256, 0, stream>>>(
        xs, wt, se, bn_gamma, bn_beta, bn_mean, bn_var, yh, yt);
    sim_mfma_kernel<<<dim3(NS_, B_), 512, 0, stream>>>(yh, simp);
    softmax_kernel<<<dim3(B_ * C_), 128, 0, stream>>>(simp, Ph);
    feat_mfma_kernel<<<dim3(HW_ / 128, B_), 256, 0, stream>>>(Ph, yt, yh, gamma, out);
}